// Round 4
// baseline (489.951 us; speedup 1.0000x reference)
//
#include <hip/hip_runtime.h>

typedef __attribute__((ext_vector_type(4))) float f32x4;
typedef __attribute__((ext_vector_type(16))) float f32x16;
typedef __attribute__((ext_vector_type(4))) unsigned short u16x4;
typedef __attribute__((ext_vector_type(4))) int i32x4;
typedef __attribute__((ext_vector_type(8))) __bf16 bf16x8;

union FragAB {
  u16x4 u[2];
  i32x4 v;
  bf16x8 f;
};

static __device__ __forceinline__ unsigned short f2bf(float x) {
  union { float f; unsigned u; } v;
  v.f = x;
  unsigned r = v.u + 0x7FFFu + ((v.u >> 16) & 1u);  // round-to-nearest-even
  return (unsigned short)(r >> 16);
}

#define NN 8192

// ---------- kernel 1: d_out = bias (broadcast) ----------
__global__ __launch_bounds__(256) void k_bias(const float* __restrict__ bias,
                                              float* __restrict__ out) {
  out[(size_t)blockIdx.x * 256 + threadIdx.x] = bias[threadIdx.x];
}

// ---------- kernel 2: Bp = (V @ Wcat)^T in k-blocked layout, bf16 ----------
// Bp element (ty, n, j) at  ty*2097152 + (j>>4)*4096 + n*16 + (j&15).
__global__ __launch_bounds__(256) void k_transform(
    const float* __restrict__ V, const float* __restrict__ w1,
    const float* __restrict__ w2, const float* __restrict__ w3,
    unsigned short* __restrict__ Bp) {
  int bx = blockIdx.x;
  int rb = bx & 63;   // j tile of 128
  int nb = bx >> 6;   // 0..11 (64-wide col tile within 768)
  const float* W = (nb < 4) ? w1 : (nb < 8) ? w2 : w3;
  int nc0 = (nb & 3) * 64;
  int tid = threadIdx.x;
  int lane = tid & 63;
  int wv = tid >> 6;
  int wm = wv >> 1, wn = wv & 1;
  int q = lane >> 4, l16 = lane & 15;

  __shared__ unsigned short tA[128][36];
  __shared__ unsigned short tB[64][36];

  f32x4 acc[4][2];
#pragma unroll
  for (int i = 0; i < 4; i++)
#pragma unroll
    for (int j = 0; j < 2; j++) acc[i][j] = (f32x4)0.0f;

  for (int kk = 0; kk < 256; kk += 32) {
    {
      int r = tid >> 1, c0 = (tid & 1) * 16;
      const float* src = V + (size_t)(rb * 128 + r) * 256 + kk + c0;
      f32x4 f0 = *(const f32x4*)(src + 0);
      f32x4 f1 = *(const f32x4*)(src + 4);
      f32x4 f2 = *(const f32x4*)(src + 8);
      f32x4 f3 = *(const f32x4*)(src + 12);
      unsigned short* d = &tA[r][c0];
      d[0] = f2bf(f0.x);  d[1] = f2bf(f0.y);  d[2] = f2bf(f0.z);  d[3] = f2bf(f0.w);
      d[4] = f2bf(f1.x);  d[5] = f2bf(f1.y);  d[6] = f2bf(f1.z);  d[7] = f2bf(f1.w);
      d[8] = f2bf(f2.x);  d[9] = f2bf(f2.y);  d[10] = f2bf(f2.z); d[11] = f2bf(f2.w);
      d[12] = f2bf(f3.x); d[13] = f2bf(f3.y); d[14] = f2bf(f3.z); d[15] = f2bf(f3.w);
    }
    {
      int r = tid >> 3, c0 = (tid & 7) * 8;
      const float* src = W + (size_t)(kk + r) * 256 + nc0 + c0;
      f32x4 g0 = *(const f32x4*)(src);
      f32x4 g1 = *(const f32x4*)(src + 4);
      tB[c0 + 0][r] = f2bf(g0.x); tB[c0 + 1][r] = f2bf(g0.y);
      tB[c0 + 2][r] = f2bf(g0.z); tB[c0 + 3][r] = f2bf(g0.w);
      tB[c0 + 4][r] = f2bf(g1.x); tB[c0 + 5][r] = f2bf(g1.y);
      tB[c0 + 6][r] = f2bf(g1.z); tB[c0 + 7][r] = f2bf(g1.w);
    }
    __syncthreads();
    FragAB af[4], bf[2];
#pragma unroll
    for (int mt = 0; mt < 4; mt++) {
      const unsigned short* p = &tA[wm * 64 + mt * 16 + l16][q * 8];
      af[mt].u[0] = *(const u16x4*)p;
      af[mt].u[1] = *(const u16x4*)(p + 4);
    }
#pragma unroll
    for (int nt = 0; nt < 2; nt++) {
      const unsigned short* p = &tB[wn * 32 + nt * 16 + l16][q * 8];
      bf[nt].u[0] = *(const u16x4*)p;
      bf[nt].u[1] = *(const u16x4*)(p + 4);
    }
#pragma unroll
    for (int mt = 0; mt < 4; mt++)
#pragma unroll
      for (int nt = 0; nt < 2; nt++)
        acc[mt][nt] = __builtin_amdgcn_mfma_f32_16x16x32_bf16(
            af[mt].f, bf[nt].f, acc[mt][nt], 0, 0, 0);
    __syncthreads();
  }
  int ty = nb >> 2;
#pragma unroll
  for (int mt = 0; mt < 4; mt++)
#pragma unroll
    for (int nt = 0; nt < 2; nt++) {
      int n = (nb & 3) * 64 + wn * 32 + nt * 16 + l16;
      int j0 = rb * 128 + wm * 64 + mt * 16 + q * 4;
      u16x4 hv;
      hv.x = f2bf(acc[mt][nt].x);
      hv.y = f2bf(acc[mt][nt].y);
      hv.z = f2bf(acc[mt][nt].z);
      hv.w = f2bf(acc[mt][nt].w);
      size_t idx = (size_t)ty * 2097152 + (size_t)(j0 >> 4) * 4096 + n * 16 + (j0 & 15);
      *(u16x4*)(Bp + idx) = hv;
    }
}

// ---------- kernel 3: out += sum_k (adj==k) @ H_k  (BARRIER-FREE) ----------
// BM=64, BN=256, BK=32, splitK=4 -> 512 blocks (2 resident/CU, LDS-limited).
// 4 waves/block, each wave: full 64 rows x its own 64-col slab (wn=wv).
// Each wave stages its own raw-adj 64x32 tile into WAVE-PRIVATE double-buffered
// LDS (xor-swizzled, conflict-free b128) -> NO __syncthreads anywhere.
// Masks built in regs at fragment-read time. B direct from global (coalesced,
// XCD-L2-resident via ks=bx&3 slicing).
__global__ __launch_bounds__(256) void k_agg(const int* __restrict__ adj,
                                             const unsigned short* __restrict__ Bp,
                                             float* __restrict__ out) {
  int bx = blockIdx.x;
  int ks = bx & 3, rb = bx >> 2;
  int tid = threadIdx.x, lane = tid & 63;
  int wv = tid >> 6;  // 0..3 = 64-col slab
  int q = lane >> 5, l32 = lane & 31;

  __shared__ __align__(16) int smem[16384];  // 4 waves x 2 bufs x 2048 ints
  int* wbase = smem + wv * 4096;

  f32x16 acc[2][2];
  acc[0][0] = (f32x16)0.0f;
  acc[0][1] = (f32x16)0.0f;
  acc[1][0] = (f32x16)0.0f;
  acc[1][1] = (f32x16)0.0f;

  // ---- staging addressing (coalesced: 8 rows x 128B segments per instr) ----
  // lane covers row (l>>3)+8j, ints (l&7)*4..+3
  const int* ast = adj + (size_t)(rb * 64 + (lane >> 3)) * NN + ks * 2048 + (lane & 7) * 4;
  int swzw = (((lane & 7) ^ ((lane >> 3) & 7)) * 4);       // xor-swizzled chunk (ints)
  int wrow = (lane >> 3) * 32;                              // row offset (ints)
  int sw7 = l32 & 7;                                        // read-side swizzle key

  // ---- B pointers: Bp + ty*2097152 + ks*524288 + n*16 + q*8 ----
  const unsigned short* bb[3][2];
#pragma unroll
  for (int ty = 0; ty < 3; ty++)
#pragma unroll
    for (int nt = 0; nt < 2; nt++) {
      int n = wv * 64 + nt * 32 + l32;
      bb[ty][nt] = Bp + (size_t)ty * 2097152 + (size_t)ks * 524288 + n * 16 + q * 8;
    }

  // ---- prologue: stage tile 0 into buf0, prefetch tile 1 into regs ----
  i32x4 st[8];
#pragma unroll
  for (int j = 0; j < 8; j++) st[j] = *(const i32x4*)(ast + j * 8 * NN);
#pragma unroll
  for (int j = 0; j < 8; j++)
    *(i32x4*)(wbase + j * 256 + wrow + swzw) = st[j];
#pragma unroll
  for (int j = 0; j < 8; j++) st[j] = *(const i32x4*)(ast + j * 8 * NN + 32);

  for (int s = 0; s < 64; s++) {
    int bufoff = (s & 1) * 2048;
    // batch-issue all 12 B loads for this step (1KB/wave each, L2-resident)
    FragAB bv[2][3][2];
    size_t soff = (size_t)s * 8192;
#pragma unroll
    for (int kh = 0; kh < 2; kh++)
#pragma unroll
      for (int ty = 0; ty < 3; ty++)
#pragma unroll
        for (int nt = 0; nt < 2; nt++)
          bv[kh][ty][nt].v = *(const i32x4*)(bb[ty][nt] + soff + kh * 4096);

    // fragments from wave-private LDS + on-the-fly mask build + MFMA
#pragma unroll
    for (int kh = 0; kh < 2; kh++)
#pragma unroll
      for (int mt = 0; mt < 2; mt++) {
        int rowoff = bufoff + mt * 1024 + l32 * 32;
        int c0 = kh * 4 + q * 2;
        i32x4 e0 = *(const i32x4*)(wbase + rowoff + ((c0 ^ sw7) * 4));
        i32x4 e1 = *(const i32x4*)(wbase + rowoff + (((c0 + 1) ^ sw7) * 4));
#pragma unroll
        for (int ty = 0; ty < 3; ty++) {
          FragAB af;
          u16x4 lo, hi;
          int t = ty + 1;
          lo.x = (e0.x == t) ? 0x3F80 : 0;
          lo.y = (e0.y == t) ? 0x3F80 : 0;
          lo.z = (e0.z == t) ? 0x3F80 : 0;
          lo.w = (e0.w == t) ? 0x3F80 : 0;
          hi.x = (e1.x == t) ? 0x3F80 : 0;
          hi.y = (e1.y == t) ? 0x3F80 : 0;
          hi.z = (e1.z == t) ? 0x3F80 : 0;
          hi.w = (e1.w == t) ? 0x3F80 : 0;
          af.u[0] = lo;
          af.u[1] = hi;
          acc[mt][0] = __builtin_amdgcn_mfma_f32_32x32x16_bf16(
              af.f, bv[kh][ty][0].f, acc[mt][0], 0, 0, 0);
          acc[mt][1] = __builtin_amdgcn_mfma_f32_32x32x16_bf16(
              af.f, bv[kh][ty][1].f, acc[mt][1], 0, 0, 0);
        }
      }

    // stage tile s+1 (already in regs) into other buf; prefetch tile s+2
    if (s < 63) {
      int obuf = bufoff ^ 2048;
#pragma unroll
      for (int j = 0; j < 8; j++)
        *(i32x4*)(wbase + obuf + j * 256 + wrow + swzw) = st[j];
      if (s < 62) {
        const int* anext = ast + (s + 2) * 32;
#pragma unroll
        for (int j = 0; j < 8; j++) st[j] = *(const i32x4*)(anext + j * 8 * NN);
      }
    }
  }

  // epilogue: C/D 32x32 layout col=lane&31, row=(reg&3)+8*(reg>>2)+4*q
#pragma unroll
  for (int mt = 0; mt < 2; mt++)
#pragma unroll
    for (int nt = 0; nt < 2; nt++) {
      int colbase = wv * 64 + nt * 32 + l32;
      int rowb = rb * 64 + mt * 32 + 4 * q;
#pragma unroll
      for (int r = 0; r < 16; r++) {
        int row = rowb + (r & 3) + 8 * (r >> 2);
        atomicAdd(out + (size_t)row * 256 + colbase, acc[mt][nt][r]);
      }
    }
}

extern "C" void kernel_launch(void* const* d_in, const int* in_sizes, int n_in,
                              void* d_out, int out_size, void* d_ws,
                              size_t ws_size, hipStream_t stream) {
  const float* V = (const float*)d_in[0];
  const int* adj = (const int*)d_in[1];
  const float* w1 = (const float*)d_in[2];
  const float* w2 = (const float*)d_in[3];
  const float* w3 = (const float*)d_in[4];
  const float* bias = (const float*)d_in[5];
  float* out = (float*)d_out;
  unsigned short* Bp = (unsigned short*)d_ws;  // 768*8192*2 = 12.6 MB

  k_bias<<<dim3(NN), dim3(256), 0, stream>>>(bias, out);
  k_transform<<<dim3(768), dim3(256), 0, stream>>>(V, w1, w2, w3, Bp);
  k_agg<<<dim3(512), dim3(256), 0, stream>>>(adj, Bp, out);
}